// Round 12
// baseline (536.071 us; speedup 1.0000x reference)
//
#include <hip/hip_runtime.h>
#include <math.h>

#define H 128
#define KE 256      // MFMA K for edge GEMM1 (k=256,257 via fp32 rank-1 update)
#define KN 256      // node GEMM1 K (2H)
#define XSTR 136    // LDS transpose-buffer row stride (elems); 272B rows (16B aligned)

typedef __attribute__((ext_vector_type(8))) short bf16x8;
typedef __attribute__((ext_vector_type(4))) float f32x4;

__device__ __forceinline__ float silu_f(float x) { return x / (1.0f + __expf(-x)); }

__device__ __forceinline__ unsigned short f2bf(float f) {
    unsigned int u = __float_as_uint(f);
    unsigned int r = u + 0x7FFFu + ((u >> 16) & 1u);
    return (unsigned short)(r >> 16);
}

// packed 2xfp32 -> 2xbf16 (hw packed cvt when available)
__device__ __forceinline__ unsigned int pkbf(float a, float b) {
#if defined(__has_builtin)
#if __has_builtin(__builtin_amdgcn_cvt_pk_bf16_f32)
    typedef __attribute__((ext_vector_type(2))) __bf16 bf16x2_t;
    bf16x2_t v = __builtin_amdgcn_cvt_pk_bf16_f32(a, b);
    return *(unsigned int*)&v;
#else
    return (unsigned int)f2bf(a) | ((unsigned int)f2bf(b) << 16);
#endif
#else
    return (unsigned int)f2bf(a) | ((unsigned int)f2bf(b) << 16);
#endif
}

// hardware packed-bf16 atomic add (gfx90a+/gfx950), fire-and-forget
__device__ __forceinline__ void atomic_pk_add_bf16(unsigned short* addr, unsigned int pkv) {
    asm volatile("global_atomic_pk_add_bf16 %0, %1, off"
                 :: "v"(addr), "v"(pkv) : "memory");
}

// ---- one weight fragment: W[K][128] fp32 -> fragment-linear Wf[f][8] bf16 ----
// (same mapping serves as A-operand [m=feat][k] or B-operand [k][n=feat])
__device__ __forceinline__ void wfrag(const float* __restrict__ W,
                                      unsigned short* __restrict__ Wf, int f) {
    int kb = f >> 9, rem = f & 511;
    int nt = rem >> 6, lane = rem & 63;
    int quad = lane >> 4, l15 = lane & 15;
    int n = nt * 16 + l15, k0 = kb * 32 + quad * 8;
    union { bf16x8 v; unsigned short u[8]; } pk;
    #pragma unroll
    for (int j = 0; j < 8; ++j) pk.u[j] = f2bf(W[(size_t)(k0 + j) * H + n]);
    *(bf16x8*)&Wf[(size_t)f * 8] = pk.v;
}

// ---- fused prep: hb convert | aggb zero (bf16) | coord copy | 5 weight transposes ----
__global__ __launch_bounds__(256) void prep_all(
    const float* __restrict__ h, unsigned short* __restrict__ hb, int n4_h,
    float* __restrict__ aggz, int n4_agg,
    const float* __restrict__ coord, float* __restrict__ coord_out, int n_coord,
    const float* __restrict__ eW1, const float* __restrict__ eW2,
    const float* __restrict__ cW1, const float* __restrict__ nW1,
    const float* __restrict__ nW2,
    unsigned short* __restrict__ eW1f, unsigned short* __restrict__ eW2f,
    unsigned short* __restrict__ cW1f, unsigned short* __restrict__ nW1f,
    unsigned short* __restrict__ nW2f,
    int b0, int b1, int b2)
{
    int b = blockIdx.x;
    int t = threadIdx.x;
    if (b < b0) {
        int i = b * 256 + t;
        if (i < n4_h) {
            float4 f = ((const float4*)h)[i];
            unsigned int lo = pkbf(f.x, f.y), hi = pkbf(f.z, f.w);
            ((uint2*)hb)[i] = make_uint2(lo, hi);
        }
    } else if (b < b1) {
        int i = (b - b0) * 256 + t;
        if (i < n4_agg) ((float4*)aggz)[i] = (float4){0.f, 0.f, 0.f, 0.f};
    } else if (b < b2) {
        int i = (b - b1) * 256 + t;
        if (i < n_coord) coord_out[i] = coord[i];
    } else {
        int idx = (b - b2) * 256 + t;
        if      (idx <  4096) wfrag(eW1, eW1f, idx);
        else if (idx <  8192) wfrag(nW1, nW1f, idx - 4096);
        else if (idx < 10240) wfrag(eW2, eW2f, idx - 8192);
        else if (idx < 12288) wfrag(cW1, cW1f, idx - 10240);
        else if (idx < 14336) wfrag(nW2, nW2f, idx - 12288);
    }
}

// ---- transposed epilogue: D[feat][edge]; lane owns edge=l15, feats nt*16+quad*4+{0..3}
// bias + LN(over feats) + SiLU; y left in acc; packed bf16 rows -> X[edge][feat]
__device__ __forceinline__ void ln_silu_t(
    f32x4* acc, const float* __restrict__ bias, const float* __restrict__ g,
    const float* __restrict__ be, unsigned short* X, int l15, int quad)
{
    float s = 0.f, q = 0.f;
    #pragma unroll
    for (int nt = 0; nt < 8; ++nt) {
        float4 b4 = *(const float4*)(bias + nt * 16 + quad * 4);
        acc[nt][0] += b4.x; acc[nt][1] += b4.y; acc[nt][2] += b4.z; acc[nt][3] += b4.w;
        #pragma unroll
        for (int r = 0; r < 4; ++r) { s += acc[nt][r]; q = fmaf(acc[nt][r], acc[nt][r], q); }
    }
    s += __shfl_xor(s, 16, 64); q += __shfl_xor(q, 16, 64);
    s += __shfl_xor(s, 32, 64); q += __shfl_xor(q, 32, 64);
    float mu   = s * 0.0078125f;
    float rstd = rsqrtf(q * 0.0078125f - mu * mu + 1e-5f);
    #pragma unroll
    for (int nt = 0; nt < 8; ++nt) {
        float4 g4 = *(const float4*)(g  + nt * 16 + quad * 4);
        float4 e4 = *(const float4*)(be + nt * 16 + quad * 4);
        float a0 = g4.x * rstd, a1 = g4.y * rstd, a2 = g4.z * rstd, a3 = g4.w * rstd;
        float y0 = silu_f(fmaf(acc[nt][0] - mu, a0, e4.x));
        float y1 = silu_f(fmaf(acc[nt][1] - mu, a1, e4.y));
        float y2 = silu_f(fmaf(acc[nt][2] - mu, a2, e4.z));
        float y3 = silu_f(fmaf(acc[nt][3] - mu, a3, e4.w));
        acc[nt][0] = y0; acc[nt][1] = y1; acc[nt][2] = y2; acc[nt][3] = y3;
        *(uint2*)&X[l15 * XSTR + nt * 16 + quad * 4] = make_uint2(pkbf(y0, y1), pkbf(y2, y3));
    }
}

// -------------------- edge kernel: 1 wave, 16 edges, transposed MFMA ----------------
__global__ __launch_bounds__(64, 4) void edge_kernel(
    const unsigned short* __restrict__ hb, const int* __restrict__ ei,
    const float* __restrict__ coord, const float* __restrict__ eattr,
    const unsigned short* __restrict__ eW1f, const float* __restrict__ eW1,
    const float* __restrict__ eb1, const float* __restrict__ eg1, const float* __restrict__ ebe1,
    const unsigned short* __restrict__ eW2f,
    const float* __restrict__ eb2, const float* __restrict__ eg2, const float* __restrict__ ebe2,
    const unsigned short* __restrict__ cW1f,
    const float* __restrict__ cb1, const float* __restrict__ cg1, const float* __restrict__ cbe1,
    const float* __restrict__ cW2,
    unsigned short* __restrict__ aggb, float* __restrict__ coord_out, int E)
{
    __shared__ unsigned short X[16 * XSTR];   // X[edge][feat], 4352 B

    const int lane = threadIdx.x;
    const int l15 = lane & 15, quad = lane >> 4;
    const int ge0 = blockIdx.x * 16;

    int el  = ge0 + l15;
    int elc = (el < E) ? el : (E - 1);
    int rowl = ei[elc], coll = ei[E + elc];
    float dx = coord[rowl * 3 + 0] - coord[coll * 3 + 0];
    float dy = coord[rowl * 3 + 1] - coord[coll * 3 + 1];
    float dz = coord[rowl * 3 + 2] - coord[coll * 3 + 2];
    float radial = dx * dx + dy * dy + dz * dz;
    float inv = 1.0f / (sqrtf(radial + 1e-8f) + 1.0f);
    float cdx = dx * inv, cdy = dy * inv, cdz = dz * inv;
    float ea = eattr[elc];

    f32x4 acc[8];
    #pragma unroll
    for (int nt = 0; nt < 8; ++nt) acc[nt] = (f32x4){0.f, 0.f, 0.f, 0.f};

    // ---- GEMM1 (transposed): A = eW1f tiles (M=feat), B = x^T from global ----
    for (int kb = 0; kb < 8; ++kb) {
        int ko = (kb & 3) * 32 + quad * 8;
        bf16x8 bfx = *(const bf16x8*)(hb + (size_t)((kb < 4) ? rowl : coll) * H + ko);
        const unsigned short* ap = eW1f + ((size_t)kb * 8) * 512 + (size_t)lane * 8;
        #pragma unroll
        for (int nt = 0; nt < 8; ++nt) {
            bf16x8 afw = *(const bf16x8*)(ap + (size_t)nt * 512);
            acc[nt] = __builtin_amdgcn_mfma_f32_16x16x32_bf16(afw, bfx, acc[nt], 0, 0, 0);
        }
    }

    // ---- rank-1 fp32 update: k=256 (radial), k=257 (eattr); per-lane scalars ----
    #pragma unroll
    for (int nt = 0; nt < 8; ++nt) {
        float4 w6 = *(const float4*)(eW1 + 256 * H + nt * 16 + quad * 4);
        float4 w7 = *(const float4*)(eW1 + 257 * H + nt * 16 + quad * 4);
        acc[nt][0] += radial * w6.x + ea * w7.x;
        acc[nt][1] += radial * w6.y + ea * w7.y;
        acc[nt][2] += radial * w6.z + ea * w7.z;
        acc[nt][3] += radial * w6.w + ea * w7.w;
    }

    // ---- epilogue 1 -> X ----
    ln_silu_t(acc, eb1, eg1, ebe1, X, l15, quad);

    // ---- GEMM2: A = eW2f, B = X rows ----
    f32x4 ac2[8];
    #pragma unroll
    for (int nt = 0; nt < 8; ++nt) ac2[nt] = (f32x4){0.f, 0.f, 0.f, 0.f};
    for (int kb = 0; kb < 4; ++kb) {
        bf16x8 bfx = *(const bf16x8*)&X[l15 * XSTR + kb * 32 + quad * 8];
        const unsigned short* ap = eW2f + ((size_t)kb * 8) * 512 + (size_t)lane * 8;
        #pragma unroll
        for (int nt = 0; nt < 8; ++nt) {
            bf16x8 afw = *(const bf16x8*)(ap + (size_t)nt * 512);
            ac2[nt] = __builtin_amdgcn_mfma_f32_16x16x32_bf16(afw, bfx, ac2[nt], 0, 0, 0);
        }
    }

    // ---- epilogue 2 = edge_feat -> X; packed agg atomics straight from registers ----
    ln_silu_t(ac2, eb2, eg2, ebe2, X, l15, quad);
    if (el < E) {
        unsigned short* ab = aggb + (size_t)rowl * H + quad * 4;
        #pragma unroll
        for (int nt = 0; nt < 8; ++nt) {
            atomic_pk_add_bf16(ab + nt * 16,     pkbf(ac2[nt][0], ac2[nt][1]));
            atomic_pk_add_bf16(ab + nt * 16 + 2, pkbf(ac2[nt][2], ac2[nt][3]));
        }
    }

    // ---- GEMM3: A = cW1f, B = X rows ----
    #pragma unroll
    for (int nt = 0; nt < 8; ++nt) acc[nt] = (f32x4){0.f, 0.f, 0.f, 0.f};
    for (int kb = 0; kb < 4; ++kb) {
        bf16x8 bfx = *(const bf16x8*)&X[l15 * XSTR + kb * 32 + quad * 8];
        const unsigned short* ap = cW1f + ((size_t)kb * 8) * 512 + (size_t)lane * 8;
        #pragma unroll
        for (int nt = 0; nt < 8; ++nt) {
            bf16x8 afw = *(const bf16x8*)(ap + (size_t)nt * 512);
            acc[nt] = __builtin_amdgcn_mfma_f32_16x16x32_bf16(afw, bfx, acc[nt], 0, 0, 0);
        }
    }

    // ---- epilogue 3: bias + LN + SiLU, dot cW2 -> cm; coord atomics ----
    {
        float s = 0.f, q = 0.f;
        #pragma unroll
        for (int nt = 0; nt < 8; ++nt) {
            float4 b4 = *(const float4*)(cb1 + nt * 16 + quad * 4);
            acc[nt][0] += b4.x; acc[nt][1] += b4.y; acc[nt][2] += b4.z; acc[nt][3] += b4.w;
            #pragma unroll
            for (int r = 0; r < 4; ++r) { s += acc[nt][r]; q = fmaf(acc[nt][r], acc[nt][r], q); }
        }
        s += __shfl_xor(s, 16, 64); q += __shfl_xor(q, 16, 64);
        s += __shfl_xor(s, 32, 64); q += __shfl_xor(q, 32, 64);
        float mu   = s * 0.0078125f;
        float rstd = rsqrtf(q * 0.0078125f - mu * mu + 1e-5f);
        float cm = 0.f;
        #pragma unroll
        for (int nt = 0; nt < 8; ++nt) {
            float4 g4 = *(const float4*)(cg1  + nt * 16 + quad * 4);
            float4 e4 = *(const float4*)(cbe1 + nt * 16 + quad * 4);
            float4 w4 = *(const float4*)(cW2  + nt * 16 + quad * 4);
            cm = fmaf(silu_f(fmaf(acc[nt][0] - mu, g4.x * rstd, e4.x)), w4.x, cm);
            cm = fmaf(silu_f(fmaf(acc[nt][1] - mu, g4.y * rstd, e4.y)), w4.y, cm);
            cm = fmaf(silu_f(fmaf(acc[nt][2] - mu, g4.z * rstd, e4.z)), w4.z, cm);
            cm = fmaf(silu_f(fmaf(acc[nt][3] - mu, g4.w * rstd, e4.w)), w4.w, cm);
        }
        cm += __shfl_xor(cm, 16, 64);
        cm += __shfl_xor(cm, 32, 64);
        if (quad < 3 && el < E) {
            float comp = (quad == 0) ? cdx : ((quad == 1) ? cdy : cdz);
            atomicAdd(&coord_out[(size_t)rowl * 3 + quad], comp * cm);
        }
    }
}

// ---- node kernel: 256 threads = 4 independent waves, 16 nodes each, transposed ----
__global__ __launch_bounds__(256, 4) void node_kernel(
    const unsigned short* __restrict__ hb, const float* __restrict__ h,
    const unsigned short* __restrict__ aggb,
    const unsigned short* __restrict__ nW1f,
    const float* __restrict__ nb1, const float* __restrict__ ng1, const float* __restrict__ nbe1,
    const unsigned short* __restrict__ nW2f, const float* __restrict__ nb2,
    float* __restrict__ out, int N)
{
    __shared__ unsigned short Xs[4][16 * XSTR];

    const int wv   = threadIdx.x >> 6;
    const int lane = threadIdx.x & 63;
    const int l15 = lane & 15, quad = lane >> 4;
    const int gn0 = (blockIdx.x * 4 + wv) * 16;
    unsigned short* X = &Xs[wv][0];

    if (gn0 >= N) return;
    int gn = gn0 + l15;
    int nl = (gn < N) ? gn : (N - 1);

    f32x4 acc[8];
    #pragma unroll
    for (int nt = 0; nt < 8; ++nt) acc[nt] = (f32x4){0.f, 0.f, 0.f, 0.f};

    // ---- GEMM1: A = nW1f, B from hb (k<128) / aggb (k>=128) ----
    for (int kb = 0; kb < 8; ++kb) {
        int ko = (kb & 3) * 32 + quad * 8;
        const unsigned short* src = (kb < 4) ? hb : aggb;
        bf16x8 bfx = *(const bf16x8*)(src + (size_t)nl * H + ko);
        const unsigned short* ap = nW1f + ((size_t)kb * 8) * 512 + (size_t)lane * 8;
        #pragma unroll
        for (int nt = 0; nt < 8; ++nt) {
            bf16x8 afw = *(const bf16x8*)(ap + (size_t)nt * 512);
            acc[nt] = __builtin_amdgcn_mfma_f32_16x16x32_bf16(afw, bfx, acc[nt], 0, 0, 0);
        }
    }

    ln_silu_t(acc, nb1, ng1, nbe1, X, l15, quad);

    // ---- GEMM2: A = nW2f, B = X rows ----
    f32x4 ac2[8];
    #pragma unroll
    for (int nt = 0; nt < 8; ++nt) ac2[nt] = (f32x4){0.f, 0.f, 0.f, 0.f};
    for (int kb = 0; kb < 4; ++kb) {
        bf16x8 bfx = *(const bf16x8*)&X[l15 * XSTR + kb * 32 + quad * 8];
        const unsigned short* ap = nW2f + ((size_t)kb * 8) * 512 + (size_t)lane * 8;
        #pragma unroll
        for (int nt = 0; nt < 8; ++nt) {
            bf16x8 afw = *(const bf16x8*)(ap + (size_t)nt * 512);
            ac2[nt] = __builtin_amdgcn_mfma_f32_16x16x32_bf16(afw, bfx, ac2[nt], 0, 0, 0);
        }
    }

    // ---- out = h + acc2 + b (float4 stores; lane owns node l15, 4 consec feats/tile) ----
    if (gn < N) {
        #pragma unroll
        for (int nt = 0; nt < 8; ++nt) {
            float4 b4 = *(const float4*)(nb2 + nt * 16 + quad * 4);
            const float4 hv = *(const float4*)(h + (size_t)gn * H + nt * 16 + quad * 4);
            float4 o;
            o.x = ac2[nt][0] + b4.x + hv.x;
            o.y = ac2[nt][1] + b4.y + hv.y;
            o.z = ac2[nt][2] + b4.z + hv.z;
            o.w = ac2[nt][3] + b4.w + hv.w;
            *(float4*)(out + (size_t)gn * H + nt * 16 + quad * 4) = o;
        }
    }
}

// -------------------- launch --------------------
extern "C" void kernel_launch(void* const* d_in, const int* in_sizes, int n_in,
                              void* d_out, int out_size, void* d_ws, size_t ws_size,
                              hipStream_t stream) {
    const float* h     = (const float*)d_in[0];
    const int*   ei    = (const int*)d_in[1];
    const float* coord = (const float*)d_in[2];
    const float* eattr = (const float*)d_in[3];
    const float* eW1   = (const float*)d_in[4];
    const float* eb1   = (const float*)d_in[5];
    const float* eg1   = (const float*)d_in[6];
    const float* ebe1  = (const float*)d_in[7];
    const float* eW2   = (const float*)d_in[8];
    const float* eb2   = (const float*)d_in[9];
    const float* eg2   = (const float*)d_in[10];
    const float* ebe2  = (const float*)d_in[11];
    const float* nW1   = (const float*)d_in[12];
    const float* nb1   = (const float*)d_in[13];
    const float* ng1   = (const float*)d_in[14];
    const float* nbe1  = (const float*)d_in[15];
    const float* nW2   = (const float*)d_in[16];
    const float* nb2   = (const float*)d_in[17];
    const float* cW1   = (const float*)d_in[18];
    const float* cb1   = (const float*)d_in[19];
    const float* cg1   = (const float*)d_in[20];
    const float* cbe1  = (const float*)d_in[21];
    const float* cW2   = (const float*)d_in[22];

    const int N = in_sizes[0] / H;
    const int E = in_sizes[1] / 2;

    float* out       = (float*)d_out;
    float* coord_out = out + (size_t)N * H;

    // ---- workspace layout (aggb bf16) ----
    char* ws = (char*)d_ws;
    size_t o = 0;
    unsigned short* aggb = (unsigned short*)(ws + o); o += (size_t)N * H * 2;
    unsigned short* hb   = (unsigned short*)(ws + o); o += (size_t)N * H * 2;
    unsigned short* eW1f = (unsigned short*)(ws + o); o += (size_t)H * KE * 2;
    unsigned short* eW2f = (unsigned short*)(ws + o); o += (size_t)H * H * 2;
    unsigned short* cW1f = (unsigned short*)(ws + o); o += (size_t)H * H * 2;
    unsigned short* nW1f = (unsigned short*)(ws + o); o += (size_t)H * KN * 2;
    unsigned short* nW2f = (unsigned short*)(ws + o); o += (size_t)H * H * 2;

    // ---- fused prep: hb | aggb zero | coord copy | weight frags ----
    const int n4_h   = N * H / 4;          // float4 groups for hb cvt
    const int n4_agg = N * H / 8;          // 16B groups over N*H*2 bytes
    const int n_co   = N * 3;
    const int b0 = (n4_h   + 255) / 256;
    const int b1 = b0 + (n4_agg + 255) / 256;
    const int b2 = b1 + (n_co   + 255) / 256;
    const int bw = (4096 + 4096 + 2048 + 2048 + 2048 + 255) / 256;  // 56
    prep_all<<<b2 + bw, 256, 0, stream>>>(
        h, hb, n4_h, (float*)aggb, n4_agg, coord, coord_out, n_co,
        eW1, eW2, cW1, nW1, nW2,
        eW1f, eW2f, cW1f, nW1f, nW2f, b0, b1, b2);

    edge_kernel<<<(E + 15) / 16, 64, 0, stream>>>(
        hb, ei, coord, eattr,
        eW1f, eW1, eb1, eg1, ebe1,
        eW2f, eb2, eg2, ebe2,
        cW1f, cb1, cg1, cbe1, cW2,
        aggb, coord_out, E);

    node_kernel<<<(N + 63) / 64, 256, 0, stream>>>(
        hb, h, aggb, nW1f, nb1, ng1, nbe1, nW2f, nb2, out, N);
}

// Round 13
// 337.213 us; speedup vs baseline: 1.5897x; 1.5897x over previous
//
#include <hip/hip_runtime.h>
#include <math.h>

#define H 128
#define KE 256      // MFMA K for edge GEMM1 (k=256,257 via fp32 rank-1 update)
#define KN 256      // node GEMM1 K (2H)
#define XSTR 136    // LDS transpose-buffer row stride (elems)

typedef __attribute__((ext_vector_type(8))) short bf16x8;
typedef __attribute__((ext_vector_type(4))) float f32x4;

__device__ __forceinline__ float silu_f(float x) { return x / (1.0f + __expf(-x)); }

__device__ __forceinline__ unsigned short f2bf(float f) {
    unsigned int u = __float_as_uint(f);
    unsigned int r = u + 0x7FFFu + ((u >> 16) & 1u);
    return (unsigned short)(r >> 16);
}

// packed 2xfp32 -> 2xbf16 (hw packed cvt when available)
__device__ __forceinline__ unsigned int pkbf(float a, float b) {
#if defined(__has_builtin)
#if __has_builtin(__builtin_amdgcn_cvt_pk_bf16_f32)
    typedef __attribute__((ext_vector_type(2))) __bf16 bf16x2_t;
    bf16x2_t v = __builtin_amdgcn_cvt_pk_bf16_f32(a, b);
    return *(unsigned int*)&v;
#else
    return (unsigned int)f2bf(a) | ((unsigned int)f2bf(b) << 16);
#endif
#else
    return (unsigned int)f2bf(a) | ((unsigned int)f2bf(b) << 16);
#endif
}

// hardware packed-bf16 atomic add (gfx90a+/gfx950), fire-and-forget
__device__ __forceinline__ void atomic_pk_add_bf16(unsigned short* addr, unsigned int pkv) {
    asm volatile("global_atomic_pk_add_bf16 %0, %1, off"
                 :: "v"(addr), "v"(pkv) : "memory");
}

// ---- 16-lane sum reduction via DPP row rotations (no LDS, pure VALU) ----
template<int CTRL>
__device__ __forceinline__ float dpp_add(float x) {
    int t = __builtin_amdgcn_update_dpp(0, __float_as_int(x), CTRL, 0xF, 0xF, true);
    return x + __int_as_float(t);
}
__device__ __forceinline__ float red16(float x) {
    x = dpp_add<0x128>(x);   // row_ror:8
    x = dpp_add<0x124>(x);   // row_ror:4
    x = dpp_add<0x122>(x);   // row_ror:2
    x = dpp_add<0x121>(x);   // row_ror:1
    return x;
}

// ---- one weight fragment: W[K][128] fp32 -> fragment-linear Wf[f][8] bf16 ----
__device__ __forceinline__ void wfrag(const float* __restrict__ W,
                                      unsigned short* __restrict__ Wf, int f) {
    int kb = f >> 9, rem = f & 511;
    int nt = rem >> 6, lane = rem & 63;
    int quad = lane >> 4, l15 = lane & 15;
    int n = nt * 16 + l15, k0 = kb * 32 + quad * 8;
    union { bf16x8 v; unsigned short u[8]; } pk;
    #pragma unroll
    for (int j = 0; j < 8; ++j) pk.u[j] = f2bf(W[(size_t)(k0 + j) * H + n]);
    *(bf16x8*)&Wf[(size_t)f * 8] = pk.v;
}

// ---- fused prep: hb convert | aggb zero (bf16) | coord copy | 5 weight transposes ----
__global__ __launch_bounds__(256) void prep_all(
    const float* __restrict__ h, unsigned short* __restrict__ hb, int n4_h,
    float* __restrict__ aggz, int n4_agg,
    const float* __restrict__ coord, float* __restrict__ coord_out, int n_coord,
    const float* __restrict__ eW1, const float* __restrict__ eW2,
    const float* __restrict__ cW1, const float* __restrict__ nW1,
    const float* __restrict__ nW2,
    unsigned short* __restrict__ eW1f, unsigned short* __restrict__ eW2f,
    unsigned short* __restrict__ cW1f, unsigned short* __restrict__ nW1f,
    unsigned short* __restrict__ nW2f,
    int b0, int b1, int b2)
{
    int b = blockIdx.x;
    int t = threadIdx.x;
    if (b < b0) {
        int i = b * 256 + t;
        if (i < n4_h) {
            float4 f = ((const float4*)h)[i];
            ((uint2*)hb)[i] = make_uint2(pkbf(f.x, f.y), pkbf(f.z, f.w));
        }
    } else if (b < b1) {
        int i = (b - b0) * 256 + t;
        if (i < n4_agg) ((float4*)aggz)[i] = (float4){0.f, 0.f, 0.f, 0.f};
    } else if (b < b2) {
        int i = (b - b1) * 256 + t;
        if (i < n_coord) coord_out[i] = coord[i];
    } else {
        int idx = (b - b2) * 256 + t;
        if      (idx <  4096) wfrag(eW1, eW1f, idx);
        else if (idx <  8192) wfrag(nW1, nW1f, idx - 4096);
        else if (idx < 10240) wfrag(eW2, eW2f, idx - 8192);
        else if (idx < 12288) wfrag(cW1, cW1f, idx - 10240);
        else if (idx < 14336) wfrag(nW2, nW2f, idx - 12288);
    }
}

// ---- single-tile epilogue: bias + LN + SiLU; result left in acc, bf16 copy in LDS ----
// X stores use hw pk cvt: 2 values -> 1 cvt; hi half stored via d16_hi write.
__device__ __forceinline__ void ln_silu_store1(
    f32x4* acc, const float* __restrict__ bias, const float* __restrict__ g,
    const float* __restrict__ be, unsigned short* X, int l15, int quad)
{
    float s[4] = {0,0,0,0}, q[4] = {0,0,0,0};
    #pragma unroll
    for (int nt = 0; nt < 8; ++nt) {
        float b = bias[nt * 16 + l15];
        #pragma unroll
        for (int r = 0; r < 4; ++r) {
            float x = acc[nt][r] + b; acc[nt][r] = x; s[r] += x; q[r] += x * x;
        }
    }
    #pragma unroll
    for (int r = 0; r < 4; ++r) { s[r] = red16(s[r]); q[r] = red16(q[r]); }
    #pragma unroll
    for (int r = 0; r < 4; ++r) {
        float mu = s[r] * 0.0078125f, v = q[r] * 0.0078125f - mu * mu;
        s[r] = mu; q[r] = rsqrtf(v + 1e-5f);
    }
    #pragma unroll
    for (int nt = 0; nt < 8; ++nt) {
        float gg = g[nt * 16 + l15], bb = be[nt * 16 + l15];
        float y0 = silu_f(fmaf(acc[nt][0], q[0] * gg, bb - s[0] * (q[0] * gg)));
        float y1 = silu_f(fmaf(acc[nt][1], q[1] * gg, bb - s[1] * (q[1] * gg)));
        float y2 = silu_f(fmaf(acc[nt][2], q[2] * gg, bb - s[2] * (q[2] * gg)));
        float y3 = silu_f(fmaf(acc[nt][3], q[3] * gg, bb - s[3] * (q[3] * gg)));
        acc[nt][0] = y0; acc[nt][1] = y1; acc[nt][2] = y2; acc[nt][3] = y3;
        unsigned int p01 = pkbf(y0, y1), p23 = pkbf(y2, y3);
        const int col = nt * 16 + l15;
        X[(quad * 4 + 0) * XSTR + col] = (unsigned short)p01;
        X[(quad * 4 + 1) * XSTR + col] = (unsigned short)(p01 >> 16);
        X[(quad * 4 + 2) * XSTR + col] = (unsigned short)p23;
        X[(quad * 4 + 3) * XSTR + col] = (unsigned short)(p23 >> 16);
    }
}

// -------------------- edge kernel: 1 wave, 16 edges, barrier-free --------------------
__global__ __launch_bounds__(64, 4) void edge_kernel(
    const unsigned short* __restrict__ hb, const int* __restrict__ ei,
    const float* __restrict__ coord, const float* __restrict__ eattr,
    const unsigned short* __restrict__ eW1f, const float* __restrict__ eW1,
    const float* __restrict__ eb1, const float* __restrict__ eg1, const float* __restrict__ ebe1,
    const unsigned short* __restrict__ eW2f,
    const float* __restrict__ eb2, const float* __restrict__ eg2, const float* __restrict__ ebe2,
    const unsigned short* __restrict__ cW1f,
    const float* __restrict__ cb1, const float* __restrict__ cg1, const float* __restrict__ cbe1,
    const float* __restrict__ cW2,
    unsigned short* __restrict__ aggb, float* __restrict__ coord_out, int E)
{
    __shared__ unsigned short X[16 * XSTR];   // 4352 B transpose buffer

    const int lane = threadIdx.x;
    const int l15 = lane & 15, quad = lane >> 4;
    const int ge0 = blockIdx.x * 16;

    int el  = ge0 + l15;
    int elc = (el < E) ? el : (E - 1);
    int rowl = ei[elc], coll = ei[E + elc];
    float dx = coord[rowl * 3 + 0] - coord[coll * 3 + 0];
    float dy = coord[rowl * 3 + 1] - coord[coll * 3 + 1];
    float dz = coord[rowl * 3 + 2] - coord[coll * 3 + 2];
    float radial = dx * dx + dy * dy + dz * dz;
    float inv = 1.0f / (sqrtf(radial + 1e-8f) + 1.0f);
    float cdx = dx * inv, cdy = dy * inv, cdz = dz * inv;
    float ea = eattr[elc];

    f32x4 acc[8];
    #pragma unroll
    for (int nt = 0; nt < 8; ++nt) acc[nt] = (f32x4){0.f, 0.f, 0.f, 0.f};

    // ---- GEMM1: [16x256] @ eW1f, A direct from global ----
    for (int kb = 0; kb < 8; ++kb) {
        int ko = (kb & 3) * 32 + quad * 8;
        bf16x8 af = *(const bf16x8*)(hb + (size_t)((kb < 4) ? rowl : coll) * H + ko);
        const unsigned short* bp = eW1f + ((size_t)kb * 8) * 512 + (size_t)lane * 8;
        #pragma unroll
        for (int nt = 0; nt < 8; ++nt) {
            bf16x8 bf = *(const bf16x8*)(bp + (size_t)nt * 512);
            acc[nt] = __builtin_amdgcn_mfma_f32_16x16x32_bf16(af, bf, acc[nt], 0, 0, 0);
        }
    }

    // ---- rank-1 fp32 update: k=256 (radial), k=257 (eattr) ----
    {
        float rad_r[4], ea_r[4];
        #pragma unroll
        for (int r = 0; r < 4; ++r) {
            rad_r[r] = __shfl(radial, quad * 4 + r, 64);
            ea_r[r]  = __shfl(ea,     quad * 4 + r, 64);
        }
        #pragma unroll
        for (int nt = 0; nt < 8; ++nt) {
            float w256 = eW1[256 * H + nt * 16 + l15];
            float w257 = eW1[257 * H + nt * 16 + l15];
            #pragma unroll
            for (int r = 0; r < 4; ++r)
                acc[nt][r] += rad_r[r] * w256 + ea_r[r] * w257;
        }
    }

    // ---- epilogue 1 -> X ----
    ln_silu_store1(acc, eb1, eg1, ebe1, X, l15, quad);

    // ---- GEMM2: [16x128] @ eW2f ----
    f32x4 ac2[8];
    #pragma unroll
    for (int nt = 0; nt < 8; ++nt) ac2[nt] = (f32x4){0.f, 0.f, 0.f, 0.f};
    for (int kb = 0; kb < 4; ++kb) {
        bf16x8 af = *(const bf16x8*)&X[l15 * XSTR + kb * 32 + quad * 8];
        const unsigned short* bp = eW2f + ((size_t)kb * 8) * 512 + (size_t)lane * 8;
        #pragma unroll
        for (int nt = 0; nt < 8; ++nt) {
            bf16x8 bf = *(const bf16x8*)(bp + (size_t)nt * 512);
            ac2[nt] = __builtin_amdgcn_mfma_f32_16x16x32_bf16(af, bf, ac2[nt], 0, 0, 0);
        }
    }

    // ---- epilogue 2 = edge_feat -> X (bf16) ----
    ln_silu_store1(ac2, eb2, eg2, ebe2, X, l15, quad);

    // ---- agg: packed-bf16 atomics, pairs read straight back from X ----
    {
        int rowm[4];
        #pragma unroll
        for (int r = 0; r < 4; ++r) rowm[r] = __shfl(rowl, quad * 4 + r, 64);
        #pragma unroll
        for (int c4 = 0; c4 < 4; ++c4) {        // col pair-group: cols c4*32 + 2*l15 (+1)
            #pragma unroll
            for (int r = 0; r < 4; ++r) {
                int geh = ge0 + quad * 4 + r;
                if (geh < E) {
                    unsigned int pkv =
                        *(const unsigned int*)&X[(quad * 4 + r) * XSTR + c4 * 32 + 2 * l15];
                    atomic_pk_add_bf16(aggb + (size_t)rowm[r] * H + c4 * 32 + 2 * l15, pkv);
                }
            }
        }
    }

    // ---- GEMM3: edge_feat @ cW1f ----
    #pragma unroll
    for (int nt = 0; nt < 8; ++nt) acc[nt] = (f32x4){0.f, 0.f, 0.f, 0.f};
    for (int kb = 0; kb < 4; ++kb) {
        bf16x8 af = *(const bf16x8*)&X[l15 * XSTR + kb * 32 + quad * 8];
        const unsigned short* bp = cW1f + ((size_t)kb * 8) * 512 + (size_t)lane * 8;
        #pragma unroll
        for (int nt = 0; nt < 8; ++nt) {
            bf16x8 bf = *(const bf16x8*)(bp + (size_t)nt * 512);
            acc[nt] = __builtin_amdgcn_mfma_f32_16x16x32_bf16(af, bf, acc[nt], 0, 0, 0);
        }
    }

    // ---- epilogue 3: bias + LN + SiLU, dot cW2 -> cm; coord atomics ----
    {
        float s[4] = {0,0,0,0}, q[4] = {0,0,0,0};
        #pragma unroll
        for (int nt = 0; nt < 8; ++nt) {
            float b = cb1[nt * 16 + l15];
            #pragma unroll
            for (int r = 0; r < 4; ++r) {
                float x = acc[nt][r] + b; acc[nt][r] = x; s[r] += x; q[r] += x * x;
            }
        }
        #pragma unroll
        for (int r = 0; r < 4; ++r) { s[r] = red16(s[r]); q[r] = red16(q[r]); }
        #pragma unroll
        for (int r = 0; r < 4; ++r) {
            float mu = s[r] * 0.0078125f, v = q[r] * 0.0078125f - mu * mu;
            s[r] = mu; q[r] = rsqrtf(v + 1e-5f);
        }
        float cm[4] = {0,0,0,0};
        #pragma unroll
        for (int nt = 0; nt < 8; ++nt) {
            float gg = cg1[nt * 16 + l15], bb = cbe1[nt * 16 + l15];
            float w2 = cW2[nt * 16 + l15];
            #pragma unroll
            for (int r = 0; r < 4; ++r) {
                float a = q[r] * gg, c = bb - s[r] * a;
                cm[r] += silu_f(acc[nt][r] * a + c) * w2;
            }
        }
        #pragma unroll
        for (int r = 0; r < 4; ++r) cm[r] = red16(cm[r]);
        #pragma unroll
        for (int r = 0; r < 4; ++r) {
            int src = quad * 4 + r;
            float cdxr = __shfl(cdx, src, 64);
            float cdyr = __shfl(cdy, src, 64);
            float cdzr = __shfl(cdz, src, 64);
            int rw = __shfl(rowl, src, 64);
            float comp = (l15 == 0) ? cdxr : ((l15 == 1) ? cdyr : cdzr);
            int geh = ge0 + src;
            if (l15 < 3 && geh < E)
                atomicAdd(&coord_out[(size_t)rw * 3 + l15], comp * cm[r]);
        }
    }
}

// ---- node kernel: 256 threads = 4 independent waves, 16 nodes each ----
__global__ __launch_bounds__(256, 4) void node_kernel(
    const unsigned short* __restrict__ hb, const float* __restrict__ h,
    const unsigned short* __restrict__ aggb,
    const unsigned short* __restrict__ nW1f,
    const float* __restrict__ nb1, const float* __restrict__ ng1, const float* __restrict__ nbe1,
    const unsigned short* __restrict__ nW2f, const float* __restrict__ nb2,
    float* __restrict__ out, int N)
{
    __shared__ unsigned short Xs[4][16 * XSTR];

    const int wv   = threadIdx.x >> 6;
    const int lane = threadIdx.x & 63;
    const int l15 = lane & 15, quad = lane >> 4;
    const int gn0 = (blockIdx.x * 4 + wv) * 16;
    unsigned short* X = &Xs[wv][0];

    if (gn0 >= N) return;
    int nl = gn0 + l15; if (nl >= N) nl = N - 1;

    f32x4 acc[8];
    #pragma unroll
    for (int nt = 0; nt < 8; ++nt) acc[nt] = (f32x4){0.f, 0.f, 0.f, 0.f};

    // ---- GEMM1: [16x256] @ nW1f; k<128 from hb, k>=128 from aggb (both bf16) ----
    for (int kb = 0; kb < 8; ++kb) {
        int ko = (kb & 3) * 32 + quad * 8;
        const unsigned short* src = (kb < 4) ? hb : aggb;
        bf16x8 af = *(const bf16x8*)(src + (size_t)nl * H + ko);
        const unsigned short* bp = nW1f + ((size_t)kb * 8) * 512 + (size_t)lane * 8;
        #pragma unroll
        for (int nt = 0; nt < 8; ++nt) {
            bf16x8 bf = *(const bf16x8*)(bp + (size_t)nt * 512);
            acc[nt] = __builtin_amdgcn_mfma_f32_16x16x32_bf16(af, bf, acc[nt], 0, 0, 0);
        }
    }

    ln_silu_store1(acc, nb1, ng1, nbe1, X, l15, quad);

    // ---- GEMM2: @ nW2f ----
    f32x4 ac2[8];
    #pragma unroll
    for (int nt = 0; nt < 8; ++nt) ac2[nt] = (f32x4){0.f, 0.f, 0.f, 0.f};
    for (int kb = 0; kb < 4; ++kb) {
        bf16x8 af = *(const bf16x8*)&X[l15 * XSTR + kb * 32 + quad * 8];
        const unsigned short* bp = nW2f + ((size_t)kb * 8) * 512 + (size_t)lane * 8;
        #pragma unroll
        for (int nt = 0; nt < 8; ++nt) {
            bf16x8 bf = *(const bf16x8*)(bp + (size_t)nt * 512);
            ac2[nt] = __builtin_amdgcn_mfma_f32_16x16x32_bf16(af, bf, ac2[nt], 0, 0, 0);
        }
    }

    // ---- out = h + acc2 + b ----
    #pragma unroll
    for (int nt = 0; nt < 8; ++nt) {
        float b = nb2[nt * 16 + l15];
        #pragma unroll
        for (int r = 0; r < 4; ++r) {
            int gn = gn0 + quad * 4 + r;
            if (gn < N) {
                size_t idx = (size_t)gn * H + nt * 16 + l15;
                out[idx] = ac2[nt][r] + b + h[idx];
            }
        }
    }
}

// -------------------- launch --------------------
extern "C" void kernel_launch(void* const* d_in, const int* in_sizes, int n_in,
                              void* d_out, int out_size, void* d_ws, size_t ws_size,
                              hipStream_t stream) {
    const float* h     = (const float*)d_in[0];
    const int*   ei    = (const int*)d_in[1];
    const float* coord = (const float*)d_in[2];
    const float* eattr = (const float*)d_in[3];
    const float* eW1   = (const float*)d_in[4];
    const float* eb1   = (const float*)d_in[5];
    const float* eg1   = (const float*)d_in[6];
    const float* ebe1  = (const float*)d_in[7];
    const float* eW2   = (const float*)d_in[8];
    const float* eb2   = (const float*)d_in[9];
    const float* eg2   = (const float*)d_in[10];
    const float* ebe2  = (const float*)d_in[11];
    const float* nW1   = (const float*)d_in[12];
    const float* nb1   = (const float*)d_in[13];
    const float* ng1   = (const float*)d_in[14];
    const float* nbe1  = (const float*)d_in[15];
    const float* nW2   = (const float*)d_in[16];
    const float* nb2   = (const float*)d_in[17];
    const float* cW1   = (const float*)d_in[18];
    const float* cb1   = (const float*)d_in[19];
    const float* cg1   = (const float*)d_in[20];
    const float* cbe1  = (const float*)d_in[21];
    const float* cW2   = (const float*)d_in[22];

    const int N = in_sizes[0] / H;
    const int E = in_sizes[1] / 2;

    float* out       = (float*)d_out;
    float* coord_out = out + (size_t)N * H;

    // ---- workspace layout (aggb bf16) ----
    char* ws = (char*)d_ws;
    size_t o = 0;
    unsigned short* aggb = (unsigned short*)(ws + o); o += (size_t)N * H * 2;
    unsigned short* hb   = (unsigned short*)(ws + o); o += (size_t)N * H * 2;
    unsigned short* eW1f = (unsigned short*)(ws + o); o += (size_t)H * KE * 2;
    unsigned short* eW2f = (unsigned short*)(ws + o); o += (size_t)H * H * 2;
    unsigned short* cW1f = (unsigned short*)(ws + o); o += (size_t)H * H * 2;
    unsigned short* nW1f = (unsigned short*)(ws + o); o += (size_t)H * KN * 2;
    unsigned short* nW2f = (unsigned short*)(ws + o); o += (size_t)H * H * 2;

    // ---- fused prep: hb | aggb zero | coord copy | weight frags ----
    const int n4_h   = N * H / 4;          // float4 groups for hb cvt
    const int n4_agg = N * H / 8;          // 16B groups over N*H*2 bytes
    const int n_co   = N * 3;
    const int b0 = (n4_h   + 255) / 256;
    const int b1 = b0 + (n4_agg + 255) / 256;
    const int b2 = b1 + (n_co   + 255) / 256;
    const int bw = (4096 + 4096 + 2048 + 2048 + 2048 + 255) / 256;  // 56
    prep_all<<<b2 + bw, 256, 0, stream>>>(
        h, hb, n4_h, (float*)aggb, n4_agg, coord, coord_out, n_co,
        eW1, eW2, cW1, nW1, nW2,
        eW1f, eW2f, cW1f, nW1f, nW2f, b0, b1, b2);

    edge_kernel<<<(E + 15) / 16, 64, 0, stream>>>(
        hb, ei, coord, eattr,
        eW1f, eW1, eb1, eg1, ebe1,
        eW2f, eb2, eg2, ebe2,
        cW1f, cb1, cg1, cbe1, cW2,
        aggb, coord_out, E);

    node_kernel<<<(N + 63) / 64, 256, 0, stream>>>(
        hb, h, aggb, nW1f, nb1, ng1, nbe1, nW2f, nb2, out, N);
}

// Round 14
// 318.454 us; speedup vs baseline: 1.6834x; 1.0589x over previous
//
#include <hip/hip_runtime.h>
#include <math.h>

#define H 128
#define KE 256      // eW1 MFMA K (k=256,257 via fp32 rank-1 update)
#define KN 256      // node GEMM1 K (2H)
#define XSTR 136    // LDS X row stride (bf16 elems)
#define SSTR 132    // LDS S row stride (fp32 elems) — breaks 4-way bank alias

typedef __attribute__((ext_vector_type(8))) short bf16x8;
typedef __attribute__((ext_vector_type(4))) float f32x4;

__device__ __forceinline__ float silu_f(float x) { return x / (1.0f + __expf(-x)); }

__device__ __forceinline__ unsigned short f2bf(float f) {
    unsigned int u = __float_as_uint(f);
    unsigned int r = u + 0x7FFFu + ((u >> 16) & 1u);
    return (unsigned short)(r >> 16);
}

__device__ __forceinline__ unsigned int pkbf(float a, float b) {
#if defined(__has_builtin)
#if __has_builtin(__builtin_amdgcn_cvt_pk_bf16_f32)
    typedef __attribute__((ext_vector_type(2))) __bf16 bf16x2_t;
    bf16x2_t v = __builtin_amdgcn_cvt_pk_bf16_f32(a, b);
    return *(unsigned int*)&v;
#else
    return (unsigned int)f2bf(a) | ((unsigned int)f2bf(b) << 16);
#endif
#else
    return (unsigned int)f2bf(a) | ((unsigned int)f2bf(b) << 16);
#endif
}

__device__ __forceinline__ float bflo(unsigned int w) { return __uint_as_float(w << 16); }
__device__ __forceinline__ float bfhi(unsigned int w) { return __uint_as_float(w & 0xFFFF0000u); }

// hardware packed-bf16 atomic add (gfx90a+/gfx950), fire-and-forget
__device__ __forceinline__ void atomic_pk_add_bf16(unsigned short* addr, unsigned int pkv) {
    asm volatile("global_atomic_pk_add_bf16 %0, %1, off"
                 :: "v"(addr), "v"(pkv) : "memory");
}

// ---- 16-lane sum reduction via DPP row rotations ----
template<int CTRL>
__device__ __forceinline__ float dpp_add(float x) {
    int t = __builtin_amdgcn_update_dpp(0, __float_as_int(x), CTRL, 0xF, 0xF, true);
    return x + __int_as_float(t);
}
__device__ __forceinline__ float red16(float x) {
    x = dpp_add<0x128>(x);
    x = dpp_add<0x124>(x);
    x = dpp_add<0x122>(x);
    x = dpp_add<0x121>(x);
    return x;
}

// ---- one weight fragment: W[K][128] fp32 -> fragment-linear Wf[f][8] bf16 ----
__device__ __forceinline__ void wfrag(const float* __restrict__ W,
                                      unsigned short* __restrict__ Wf, int f) {
    int kb = f >> 9, rem = f & 511;
    int nt = rem >> 6, lane = rem & 63;
    int quad = lane >> 4, l15 = lane & 15;
    int n = nt * 16 + l15, k0 = kb * 32 + quad * 8;
    union { bf16x8 v; unsigned short u[8]; } pk;
    #pragma unroll
    for (int j = 0; j < 8; ++j) pk.u[j] = f2bf(W[(size_t)(k0 + j) * H + n]);
    *(bf16x8*)&Wf[(size_t)f * 8] = pk.v;
}

// ---- fused prep: hb convert | aggb zero | coord copy | 5 weight transposes ----
__global__ __launch_bounds__(256) void prep_all(
    const float* __restrict__ h, unsigned short* __restrict__ hb, int n4_h,
    float* __restrict__ aggz, int n4_agg,
    const float* __restrict__ coord, float* __restrict__ coord_out, int n_coord,
    const float* __restrict__ eW1, const float* __restrict__ eW2,
    const float* __restrict__ cW1, const float* __restrict__ nW1,
    const float* __restrict__ nW2,
    unsigned short* __restrict__ eW1f, unsigned short* __restrict__ eW2f,
    unsigned short* __restrict__ cW1f, unsigned short* __restrict__ nW1f,
    unsigned short* __restrict__ nW2f,
    int b0, int b1, int b2)
{
    int b = blockIdx.x;
    int t = threadIdx.x;
    if (b < b0) {
        int i = b * 256 + t;
        if (i < n4_h) {
            float4 f = ((const float4*)h)[i];
            ((uint2*)hb)[i] = make_uint2(pkbf(f.x, f.y), pkbf(f.z, f.w));
        }
    } else if (b < b1) {
        int i = (b - b0) * 256 + t;
        if (i < n4_agg) ((float4*)aggz)[i] = (float4){0.f, 0.f, 0.f, 0.f};
    } else if (b < b2) {
        int i = (b - b1) * 256 + t;
        if (i < n_coord) coord_out[i] = coord[i];
    } else {
        int idx = (b - b2) * 256 + t;
        if      (idx <  4096) wfrag(eW1, eW1f, idx);
        else if (idx <  8192) wfrag(nW1, nW1f, idx - 4096);
        else if (idx < 10240) wfrag(eW2, eW2f, idx - 8192);
        else if (idx < 12288) wfrag(cW1, cW1f, idx - 10240);
        else if (idx < 14336) wfrag(nW2, nW2f, idx - 12288);
    }
}

// ---- proj kernel: Pb[n][0:128] = h[n]@eW1[0:128,:], Pb[n][128:256] = h[n]@eW1[128:256,:]
__global__ __launch_bounds__(256, 4) void proj_kernel(
    const unsigned short* __restrict__ hb,
    const unsigned short* __restrict__ eW1f,
    unsigned short* __restrict__ Pb, int N)
{
    __shared__ unsigned short Ys[4][16 * 256];   // 8 KB per wave

    const int wv = threadIdx.x >> 6;
    const int lane = threadIdx.x & 63;
    const int l15 = lane & 15, quad = lane >> 4;
    const int gn0 = (blockIdx.x * 4 + wv) * 16;
    unsigned short* Y = &Ys[wv][0];

    if (gn0 >= N) return;
    int nl = gn0 + l15; if (nl >= N) nl = N - 1;

    f32x4 a1[8], a2[8];
    #pragma unroll
    for (int nt = 0; nt < 8; ++nt) {
        a1[nt] = (f32x4){0.f, 0.f, 0.f, 0.f};
        a2[nt] = (f32x4){0.f, 0.f, 0.f, 0.f};
    }

    for (int kb = 0; kb < 4; ++kb) {
        int ko = kb * 32 + quad * 8;
        bf16x8 af = *(const bf16x8*)(hb + (size_t)nl * H + ko);
        const unsigned short* bp1 = eW1f + ((size_t)kb * 8) * 512 + (size_t)lane * 8;
        const unsigned short* bp2 = eW1f + ((size_t)(kb + 4) * 8) * 512 + (size_t)lane * 8;
        #pragma unroll
        for (int nt = 0; nt < 8; ++nt) {
            bf16x8 b1 = *(const bf16x8*)(bp1 + (size_t)nt * 512);
            bf16x8 b2 = *(const bf16x8*)(bp2 + (size_t)nt * 512);
            a1[nt] = __builtin_amdgcn_mfma_f32_16x16x32_bf16(af, b1, a1[nt], 0, 0, 0);
            a2[nt] = __builtin_amdgcn_mfma_f32_16x16x32_bf16(af, b2, a2[nt], 0, 0, 0);
        }
    }

    // C-layout -> LDS bf16 rows [node][256]
    #pragma unroll
    for (int nt = 0; nt < 8; ++nt) {
        int c = nt * 16 + l15;
        #pragma unroll
        for (int r = 0; r < 4; ++r) {
            int rr = quad * 4 + r;
            Y[rr * 256 + c]       = f2bf(a1[nt][r]);
            Y[rr * 256 + 128 + c] = f2bf(a2[nt][r]);
        }
    }

    // coalesced copy-out: 4 lanes per node, 8 x 16B each
    const int m = lane >> 2, part = lane & 3;
    int gm = gn0 + m; if (gm >= N) gm = N - 1;
    #pragma unroll
    for (int j = 0; j < 8; ++j) {
        uint4 v = *(const uint4*)&Y[m * 256 + part * 64 + j * 8];
        *(uint4*)(Pb + (size_t)gm * 256 + part * 64 + j * 8) = v;
    }
}

// ---- single-tile epilogue: bias + LN + SiLU; result in acc, bf16 copy in LDS X ----
__device__ __forceinline__ void ln_silu_store1(
    f32x4* acc, const float* __restrict__ bias, const float* __restrict__ g,
    const float* __restrict__ be, unsigned short* X, int l15, int quad)
{
    float s[4] = {0,0,0,0}, q[4] = {0,0,0,0};
    #pragma unroll
    for (int nt = 0; nt < 8; ++nt) {
        float b = bias[nt * 16 + l15];
        #pragma unroll
        for (int r = 0; r < 4; ++r) {
            float x = acc[nt][r] + b; acc[nt][r] = x; s[r] += x; q[r] += x * x;
        }
    }
    #pragma unroll
    for (int r = 0; r < 4; ++r) { s[r] = red16(s[r]); q[r] = red16(q[r]); }
    #pragma unroll
    for (int r = 0; r < 4; ++r) {
        float mu = s[r] * 0.0078125f, v = q[r] * 0.0078125f - mu * mu;
        s[r] = mu; q[r] = rsqrtf(v + 1e-5f);
    }
    #pragma unroll
    for (int nt = 0; nt < 8; ++nt) {
        float gg = g[nt * 16 + l15], bb = be[nt * 16 + l15];
        #pragma unroll
        for (int r = 0; r < 4; ++r) {
            float a = q[r] * gg, c = bb - s[r] * a;
            float y = silu_f(fmaf(acc[nt][r], a, c));
            acc[nt][r] = y;
            X[(quad * 4 + r) * XSTR + nt * 16 + l15] = f2bf(y);
        }
    }
}

// -------------------- edge kernel: 1 wave, 16 edges, GEMM1 replaced by P-gather ----
__global__ __launch_bounds__(64, 4) void edge_kernel(
    const unsigned short* __restrict__ Pb, const int* __restrict__ ei,
    const float* __restrict__ coord, const float* __restrict__ eattr,
    const float* __restrict__ eW1,
    const float* __restrict__ eb1, const float* __restrict__ eg1, const float* __restrict__ ebe1,
    const unsigned short* __restrict__ eW2f,
    const float* __restrict__ eb2, const float* __restrict__ eg2, const float* __restrict__ ebe2,
    const unsigned short* __restrict__ cW1f,
    const float* __restrict__ cb1, const float* __restrict__ cg1, const float* __restrict__ cbe1,
    const float* __restrict__ cW2,
    unsigned short* __restrict__ aggb, float* __restrict__ coord_out, int E)
{
    __shared__ float S[16 * SSTR];                 // 8448 B; X aliases S
    unsigned short* X = (unsigned short*)S;

    const int lane = threadIdx.x;
    const int l15 = lane & 15, quad = lane >> 4;
    const int ge0 = blockIdx.x * 16;

    int el  = ge0 + l15;
    int elc = (el < E) ? el : (E - 1);
    int rowl = ei[elc], coll = ei[E + elc];
    float dx = coord[rowl * 3 + 0] - coord[coll * 3 + 0];
    float dy = coord[rowl * 3 + 1] - coord[coll * 3 + 1];
    float dz = coord[rowl * 3 + 2] - coord[coll * 3 + 2];
    float radial = dx * dx + dy * dy + dz * dz;
    float inv = 1.0f / (sqrtf(radial + 1e-8f) + 1.0f);
    float cdx = dx * inv, cdy = dy * inv, cdz = dz * inv;
    float ea = eattr[elc];

    // ---- stage P1[row] + P2[col] (bf16) summed to fp32 S[edge][128] ----
    {
        const int m = lane >> 2, part = lane & 3;
        int row_m = __shfl(rowl, m, 64);
        int col_m = __shfl(coll, m, 64);
        const unsigned short* p1 = Pb + (size_t)row_m * 256 + part * 32;
        const unsigned short* p2 = Pb + (size_t)col_m * 256 + 128 + part * 32;
        #pragma unroll
        for (int j = 0; j < 4; ++j) {
            uint4 a = *(const uint4*)(p1 + j * 8);
            uint4 b = *(const uint4*)(p2 + j * 8);
            float4 v0, v1;
            v0.x = bflo(a.x) + bflo(b.x); v0.y = bfhi(a.x) + bfhi(b.x);
            v0.z = bflo(a.y) + bflo(b.y); v0.w = bfhi(a.y) + bfhi(b.y);
            v1.x = bflo(a.z) + bflo(b.z); v1.y = bfhi(a.z) + bfhi(b.z);
            v1.z = bflo(a.w) + bflo(b.w); v1.w = bfhi(a.w) + bfhi(b.w);
            *(float4*)&S[m * SSTR + part * 32 + j * 8]     = v0;
            *(float4*)&S[m * SSTR + part * 32 + j * 8 + 4] = v1;
        }
    }

    // ---- acc init: C-layout read of S + rank-1 fp32 update (k=256,257) ----
    f32x4 acc[8];
    {
        float rad_r[4], ea_r[4];
        #pragma unroll
        for (int r = 0; r < 4; ++r) {
            rad_r[r] = __shfl(radial, quad * 4 + r, 64);
            ea_r[r]  = __shfl(ea,     quad * 4 + r, 64);
        }
        #pragma unroll
        for (int nt = 0; nt < 8; ++nt) {
            float w256 = eW1[256 * H + nt * 16 + l15];
            float w257 = eW1[257 * H + nt * 16 + l15];
            #pragma unroll
            for (int r = 0; r < 4; ++r) {
                float base = S[(quad * 4 + r) * SSTR + nt * 16 + l15];
                acc[nt][r] = base + rad_r[r] * w256 + ea_r[r] * w257;
            }
        }
    }

    // ---- epilogue 1 -> X (aliases S; all S reads precede these writes, in-wave order) ----
    ln_silu_store1(acc, eb1, eg1, ebe1, X, l15, quad);

    // ---- GEMM2: [16x128] @ eW2f ----
    f32x4 ac2[8];
    #pragma unroll
    for (int nt = 0; nt < 8; ++nt) ac2[nt] = (f32x4){0.f, 0.f, 0.f, 0.f};
    for (int kb = 0; kb < 4; ++kb) {
        bf16x8 af = *(const bf16x8*)&X[l15 * XSTR + kb * 32 + quad * 8];
        const unsigned short* bp = eW2f + ((size_t)kb * 8) * 512 + (size_t)lane * 8;
        #pragma unroll
        for (int nt = 0; nt < 8; ++nt) {
            bf16x8 bf = *(const bf16x8*)(bp + (size_t)nt * 512);
            ac2[nt] = __builtin_amdgcn_mfma_f32_16x16x32_bf16(af, bf, ac2[nt], 0, 0, 0);
        }
    }

    // ---- epilogue 2 = edge_feat -> X ----
    ln_silu_store1(ac2, eb2, eg2, ebe2, X, l15, quad);

    // ---- agg: packed-bf16 atomics, pairs read straight back from X (R11 pattern) ----
    {
        int rowm[4];
        #pragma unroll
        for (int r = 0; r < 4; ++r) rowm[r] = __shfl(rowl, quad * 4 + r, 64);
        #pragma unroll
        for (int c4 = 0; c4 < 4; ++c4) {
            #pragma unroll
            for (int r = 0; r < 4; ++r) {
                int geh = ge0 + quad * 4 + r;
                if (geh < E) {
                    unsigned int pkv =
                        *(const unsigned int*)&X[(quad * 4 + r) * XSTR + c4 * 32 + 2 * l15];
                    atomic_pk_add_bf16(aggb + (size_t)rowm[r] * H + c4 * 32 + 2 * l15, pkv);
                }
            }
        }
    }

    // ---- GEMM3: edge_feat @ cW1f ----
    #pragma unroll
    for (int nt = 0; nt < 8; ++nt) acc[nt] = (f32x4){0.f, 0.f, 0.f, 0.f};
    for (int kb = 0; kb < 4; ++kb) {
        bf16x8 af = *(const bf16x8*)&X[l15 * XSTR + kb * 32 + quad * 8];
        const unsigned short* bp = cW1f + ((size_t)kb * 8) * 512 + (size_t)lane * 8;
        #pragma unroll
        for (int nt = 0; nt < 8; ++nt) {
            bf16x8 bf = *(const bf16x8*)(bp + (size_t)nt * 512);
            acc[nt] = __builtin_amdgcn_mfma_f32_16x16x32_bf16(af, bf, acc[nt], 0, 0, 0);
        }
    }

    // ---- epilogue 3: bias + LN + SiLU, dot cW2 -> cm; coord atomics ----
    {
        float s[4] = {0,0,0,0}, q[4] = {0,0,0,0};
        #pragma unroll
        for (int nt = 0; nt < 8; ++nt) {
            float b = cb1[nt * 16 + l15];
            #pragma unroll
            for (int r = 0; r < 4; ++r) {
                float x = acc[nt][r] + b; acc[nt][r] = x; s[r] += x; q[r] += x * x;
            }
        }
        #pragma unroll
        for (int r = 0; r < 4; ++r) { s[r] = red16(s[r]); q[r] = red16(q[r]); }
        #pragma unroll
        for (int r = 0; r < 4; ++r) {
            float mu = s[r] * 0.0078125f, v = q[r] * 0.0078125f - mu * mu;
            s[r] = mu; q[r] = rsqrtf(v + 1e-5f);
        }
        float cm[4] = {0,0,0,0};
        #pragma unroll
        for (int nt = 0; nt < 8; ++nt) {
            float gg = cg1[nt * 16 + l15], bb = cbe1[nt * 16 + l15];
            float w2 = cW2[nt * 16 + l15];
            #pragma unroll
            for (int r = 0; r < 4; ++r) {
                float a = q[r] * gg, c = bb - s[r] * a;
                cm[r] += silu_f(fmaf(acc[nt][r], a, c)) * w2;
            }
        }
        #pragma unroll
        for (int r = 0; r < 4; ++r) cm[r] = red16(cm[r]);
        #pragma unroll
        for (int r = 0; r < 4; ++r) {
            int src = quad * 4 + r;
            float cdxr = __shfl(cdx, src, 64);
            float cdyr = __shfl(cdy, src, 64);
            float cdzr = __shfl(cdz, src, 64);
            int rw = __shfl(rowl, src, 64);
            float comp = (l15 == 0) ? cdxr : ((l15 == 1) ? cdyr : cdzr);
            int geh = ge0 + src;
            if (l15 < 3 && geh < E)
                atomicAdd(&coord_out[(size_t)rw * 3 + l15], comp * cm[r]);
        }
    }
}

// ---- node kernel: 256 threads = 4 independent waves, 16 nodes each ----
__global__ __launch_bounds__(256, 4) void node_kernel(
    const unsigned short* __restrict__ hb, const float* __restrict__ h,
    const unsigned short* __restrict__ aggb,
    const unsigned short* __restrict__ nW1f,
    const float* __restrict__ nb1, const float* __restrict__ ng1, const float* __restrict__ nbe1,
    const unsigned short* __restrict__ nW2f, const float* __restrict__ nb2,
    float* __restrict__ out, int N)
{
    __shared__ unsigned short Xs[4][16 * XSTR];

    const int wv   = threadIdx.x >> 6;
    const int lane = threadIdx.x & 63;
    const int l15 = lane & 15, quad = lane >> 4;
    const int gn0 = (blockIdx.x * 4 + wv) * 16;
    unsigned short* X = &Xs[wv][0];

    if (gn0 >= N) return;
    int nl = gn0 + l15; if (nl >= N) nl = N - 1;

    f32x4 acc[8];
    #pragma unroll
    for (int nt = 0; nt < 8; ++nt) acc[nt] = (f32x4){0.f, 0.f, 0.f, 0.f};

    for (int kb = 0; kb < 8; ++kb) {
        int ko = (kb & 3) * 32 + quad * 8;
        const unsigned short* src = (kb < 4) ? hb : aggb;
        bf16x8 af = *(const bf16x8*)(src + (size_t)nl * H + ko);
        const unsigned short* bp = nW1f + ((size_t)kb * 8) * 512 + (size_t)lane * 8;
        #pragma unroll
        for (int nt = 0; nt < 8; ++nt) {
            bf16x8 bf = *(const bf16x8*)(bp + (size_t)nt * 512);
            acc[nt] = __builtin_amdgcn_mfma_f32_16x16x32_bf16(af, bf, acc[nt], 0, 0, 0);
        }
    }

    ln_silu_store1(acc, nb1, ng1, nbe1, X, l15, quad);

    f32x4 ac2[8];
    #pragma unroll
    for (int nt = 0; nt < 8; ++nt) ac2[nt] = (f32x4){0.f, 0.f, 0.f, 0.f};
    for (int kb = 0; kb < 4; ++kb) {
        bf16x8 af = *(const bf16x8*)&X[l15 * XSTR + kb * 32 + quad * 8];
        const unsigned short* bp = nW2f + ((size_t)kb * 8) * 512 + (size_t)lane * 8;
        #pragma unroll
        for (int nt = 0; nt < 8; ++nt) {
            bf16x8 bf = *(const bf16x8*)(bp + (size_t)nt * 512);
            ac2[nt] = __builtin_amdgcn_mfma_f32_16x16x32_bf16(af, bf, ac2[nt], 0, 0, 0);
        }
    }

    #pragma unroll
    for (int nt = 0; nt < 8; ++nt) {
        float b = nb2[nt * 16 + l15];
        #pragma unroll
        for (int r = 0; r < 4; ++r) {
            int gn = gn0 + quad * 4 + r;
            if (gn < N) {
                size_t idx = (size_t)gn * H + nt * 16 + l15;
                out[idx] = ac2[nt][r] + b + h[idx];
            }
        }
    }
}

// -------------------- launch --------------------
extern "C" void kernel_launch(void* const* d_in, const int* in_sizes, int n_in,
                              void* d_out, int out_size, void* d_ws, size_t ws_size,
                              hipStream_t stream) {
    const float* h     = (const float*)d_in[0];
    const int*   ei    = (const int*)d_in[1];
    const float* coord = (const float*)d_in[2];
    const float* eattr = (const float*)d_in[3];
    const float* eW1   = (const float*)d_in[4];
    const float* eb1   = (const float*)d_in[5];
    const float* eg1   = (const float*)d_in[6];
    const float* ebe1  = (const float*)d_in[7];
    const float* eW2   = (const float*)d_in[8];
    const float* eb2   = (const float*)d_in[9];
    const float* eg2   = (const float*)d_in[10];
    const float* ebe2  = (const float*)d_in[11];
    const float* nW1   = (const float*)d_in[12];
    const float* nb1   = (const float*)d_in[13];
    const float* ng1   = (const float*)d_in[14];
    const float* nbe1  = (const float*)d_in[15];
    const float* nW2   = (const float*)d_in[16];
    const float* nb2   = (const float*)d_in[17];
    const float* cW1   = (const float*)d_in[18];
    const float* cb1   = (const float*)d_in[19];
    const float* cg1   = (const float*)d_in[20];
    const float* cbe1  = (const float*)d_in[21];
    const float* cW2   = (const float*)d_in[22];

    const int N = in_sizes[0] / H;
    const int E = in_sizes[1] / 2;

    float* out       = (float*)d_out;
    float* coord_out = out + (size_t)N * H;

    // ---- workspace layout ----
    char* ws = (char*)d_ws;
    size_t o = 0;
    unsigned short* aggb = (unsigned short*)(ws + o); o += (size_t)N * H * 2;
    unsigned short* hb   = (unsigned short*)(ws + o); o += (size_t)N * H * 2;
    unsigned short* Pb   = (unsigned short*)(ws + o); o += (size_t)N * 256 * 2;
    unsigned short* eW1f = (unsigned short*)(ws + o); o += (size_t)H * KE * 2;
    unsigned short* eW2f = (unsigned short*)(ws + o); o += (size_t)H * H * 2;
    unsigned short* cW1f = (unsigned short*)(ws + o); o += (size_t)H * H * 2;
    unsigned short* nW1f = (unsigned short*)(ws + o); o += (size_t)H * KN * 2;
    unsigned short* nW2f = (unsigned short*)(ws + o); o += (size_t)H * H * 2;

    // ---- fused prep: hb | aggb zero | coord copy | weight frags ----
    const int n4_h   = N * H / 4;
    const int n4_agg = N * H / 8;          // 16B groups over N*H*2 bytes
    const int n_co   = N * 3;
    const int b0 = (n4_h   + 255) / 256;
    const int b1 = b0 + (n4_agg + 255) / 256;
    const int b2 = b1 + (n_co   + 255) / 256;
    const int bw = (4096 + 4096 + 2048 + 2048 + 2048 + 255) / 256;  // 56
    prep_all<<<b2 + bw, 256, 0, stream>>>(
        h, hb, n4_h, (float*)aggb, n4_agg, coord, coord_out, n_co,
        eW1, eW2, cW1, nW1, nW2,
        eW1f, eW2f, cW1f, nW1f, nW2f, b0, b1, b2);

    proj_kernel<<<(N + 63) / 64, 256, 0, stream>>>(hb, eW1f, Pb, N);

    edge_kernel<<<(E + 15) / 16, 64, 0, stream>>>(
        Pb, ei, coord, eattr,
        eW1, eb1, eg1, ebe1,
        eW2f, eb2, eg2, ebe2,
        cW1f, cb1, cg1, cbe1, cW2,
        aggb, coord_out, E);

    node_kernel<<<(N + 63) / 64, 256, 0, stream>>>(
        hb, h, aggb, nW1f, nb1, ng1, nbe1, nW2f, nb2, out, N);
}